// Round 4
// baseline (853.285 us; speedup 1.0000x reference)
//
#include <hip/hip_runtime.h>
#include <stdint.h>

typedef __attribute__((ext_vector_type(8))) short short8;
typedef __attribute__((ext_vector_type(4))) float floatx4;
typedef __attribute__((ext_vector_type(4))) unsigned uintx4;

__device__ __forceinline__ unsigned short f2bf(float f) {
    unsigned u = __float_as_uint(f);
    u += 0x7FFFu + ((u >> 16) & 1u);
    return (unsigned short)(u >> 16);
}

__device__ __forceinline__ void gload_lds16(const void* g, void* l) {
    __builtin_amdgcn_global_load_lds(
        (const __attribute__((address_space(1))) unsigned int*)g,
        (__attribute__((address_space(3))) unsigned int*)l, 16, 0, 0);
}

// ---- prep: X fp32 -> bf16 (same layout) ----
__global__ __launch_bounds__(256)
void conv_x(const float* __restrict__ x, unsigned short* __restrict__ xb) {
    const size_t total = (size_t)16384 * 1024;
    for (size_t i = ((size_t)blockIdx.x * 256 + threadIdx.x) * 8; i < total;
         i += (size_t)2048 * 256 * 8) {
        float4 a = *(const float4*)&x[i];
        float4 b = *(const float4*)&x[i + 4];
        uint4 o;
        o.x = f2bf(a.x) | ((unsigned)f2bf(a.y) << 16);
        o.y = f2bf(a.z) | ((unsigned)f2bf(a.w) << 16);
        o.z = f2bf(b.x) | ((unsigned)f2bf(b.y) << 16);
        o.w = f2bf(b.z) | ((unsigned)f2bf(b.w) << 16);
        *(uint4*)&xb[i] = o;
    }
}

// ---- prep: W [1024][N] fp32 -> Wt [N][1024] bf16 (LDS-tiled transpose) ----
__global__ __launch_bounds__(256)
void transpose_w(const float* __restrict__ src, unsigned short* __restrict__ dst, int N) {
    __shared__ float T[64][65];
    const int t = threadIdx.x;
    const int k0 = blockIdx.x * 64, n0 = blockIdx.y * 64;
    const int r = t >> 4, c4 = (t & 15) * 4;
#pragma unroll
    for (int i = 0; i < 4; i++) {
        float4 v = *(const float4*)&src[(size_t)(k0 + r + 16 * i) * N + n0 + c4];
        T[r + 16 * i][c4] = v.x; T[r + 16 * i][c4 + 1] = v.y;
        T[r + 16 * i][c4 + 2] = v.z; T[r + 16 * i][c4 + 3] = v.w;
    }
    __syncthreads();
#pragma unroll
    for (int i = 0; i < 4; i++) {
        const int n = n0 + r + 16 * i;
        unsigned short b0 = f2bf(T[c4 + 0][r + 16 * i]);
        unsigned short b1 = f2bf(T[c4 + 1][r + 16 * i]);
        unsigned short b2 = f2bf(T[c4 + 2][r + 16 * i]);
        unsigned short b3 = f2bf(T[c4 + 3][r + 16 * i]);
        uint2 pv;
        pv.x = b0 | ((unsigned)b1 << 16);
        pv.y = b2 | ((unsigned)b3 << 16);
        *(uint2*)&dst[(size_t)n * 1024 + k0 + c4] = pv;
    }
}

__global__ __launch_bounds__(128)
void pack_bias(const float* __restrict__ bq, const float* __restrict__ bk,
               float* __restrict__ bqk) {
    const int t = threadIdx.x;
    bqk[t] = (t < 64) ? bq[t] : bk[t - 64];
}

// ---- m97-style 128x128 bf16 GEMM: C = A[M][1024] @ Bt[N][1024]^T + bias ----
template<bool TRS>
__global__ __launch_bounds__(256)
void gemm_bf16(const unsigned short* __restrict__ A,
               const unsigned short* __restrict__ Bt,
               const float* __restrict__ bias,
               unsigned short* __restrict__ out, int M, int N)
{
    __shared__ unsigned short As[128 * 32];
    __shared__ unsigned short Bs[128 * 32];
    const int tid = threadIdx.x;
    const int w = tid >> 6, l = tid & 63;
    const int quad = l >> 4, l16 = l & 15;
    const int wr = w >> 1, wc = w & 1;
    const int m0 = blockIdx.x * 128, n0 = blockIdx.y * 128;

    const int lr = l >> 2, lk = (l & 3) * 8;
    const unsigned short* Ag0 = A + (size_t)(m0 + w * 16 + lr) * 1024 + lk;
    const unsigned short* Ag1 = Ag0 + (size_t)64 * 1024;
    const unsigned short* Bg0 = Bt + (size_t)(n0 + w * 16 + lr) * 1024 + lk;
    const unsigned short* Bg1 = Bg0 + (size_t)64 * 1024;
    unsigned short* Al0 = &As[w * 512 + l * 8];
    unsigned short* Bl0 = &Bs[w * 512 + l * 8];

    floatx4 acc[4][4];
#pragma unroll
    for (int i = 0; i < 4; i++)
#pragma unroll
        for (int j = 0; j < 4; j++) acc[i][j] = (floatx4)0.f;

    for (int e0 = 0; e0 < 1024; e0 += 32) {
        gload_lds16(Ag0 + e0, Al0);
        gload_lds16(Ag1 + e0, Al0 + 2048);
        gload_lds16(Bg0 + e0, Bl0);
        gload_lds16(Bg1 + e0, Bl0 + 2048);
        __syncthreads();
        short8 af[4], bf[4];
#pragma unroll
        for (int i = 0; i < 4; i++)
            af[i] = *(const short8*)&As[(wr * 64 + i * 16 + l16) * 32 + quad * 8];
#pragma unroll
        for (int j = 0; j < 4; j++)
            bf[j] = *(const short8*)&Bs[(wc * 64 + j * 16 + l16) * 32 + quad * 8];
#pragma unroll
        for (int i = 0; i < 4; i++)
#pragma unroll
            for (int j = 0; j < 4; j++)
                acc[i][j] = __builtin_amdgcn_mfma_f32_16x16x32_bf16(af[i], bf[j], acc[i][j], 0, 0, 0);
        __syncthreads();
    }

#pragma unroll
    for (int j = 0; j < 4; j++) {
        const int n = n0 + wc * 64 + j * 16 + l16;
        const float bn = bias[n];
#pragma unroll
        for (int i = 0; i < 4; i++) {
            const int mb = m0 + wr * 64 + i * 16 + quad * 4;
            if (TRS) {
                unsigned short t[4];
#pragma unroll
                for (int r = 0; r < 4; r++) t[r] = f2bf(acc[i][j][r] + bn);
                uint2 pv;
                pv.x = t[0] | ((unsigned)t[1] << 16);
                pv.y = t[2] | ((unsigned)t[3] << 16);
                *(uint2*)&out[(size_t)n * M + mb] = pv;
            } else {
#pragma unroll
                for (int r = 0; r < 4; r++)
                    out[(size_t)(mb + r) * N + n] = f2bf(acc[i][j][r] + bn);
            }
        }
    }
}

// ---- attention v7: fully wave-independent. No LDS, no barriers.
//      Each wave: 16 q rows x 256 dv. S^T = mfma(K,Q) puts P row-local
//      (q-row = l16); cvt_pk + permlane32/16_swap builds the PV A-fragment
//      in registers. Row sums stay per-lane (single scalar).
__global__ __launch_bounds__(256, 4)
void attn_fused(const unsigned short* __restrict__ QKb, // 16384 x 128 bf16 (Q|K)
                const unsigned short* __restrict__ Vt,  // 1024 x 16384 bf16 (dv, bs)
                const float* __restrict__ maskx,        // 4 x 4096
                float* __restrict__ out)                // 4 x 4096 x 1024
{
    const int tid = threadIdx.x;
    const int wave = tid >> 6, lane = tid & 63;
    const int quad = lane >> 4, l16 = lane & 15;
    const int bid = blockIdx.x;
    // bid bits: [t:6][b:2][dvq:2] -> per XCD slot: fixed (b, dv quarter pair)
    const int dvq = bid & 3;
    const int b = (bid >> 2) & 3;
    const int t = bid >> 4;                 // 0..63
    const int qt = (t < 32) ? (63 - t) : (t - 32);  // per-CU qt sums constant
    const int q0 = qt * 64;
    const int rb = wave;                    // 16-row block 0..3
    const int qrow = q0 + rb * 16 + l16;    // this lane's q-row (S^T layout)
    const int dv0 = dvq * 256;

    // Q B-fragment: rows rb*16+l16, d = quad*8 (+32)
    const unsigned short* qrp = QKb + (size_t)(b * 4096 + qrow) * 128 + quad * 8;
    const short8 qa0 = *(const short8*)qrp;
    const short8 qa1 = *(const short8*)(qrp + 32);

    const bool pq = maskx[b * 4096 + qrow] < -1e30f;

    floatx4 acc[16];
#pragma unroll
    for (int cb = 0; cb < 16; cb++) acc[cb] = (floatx4)0.f;
    float lacc = 0.f;

    const int niter = 2 * qt + 2;
    const float scale = 0.125f;

    // K A-fragment base: key = k0 + kt_*16 + l16, d = 64 + dc*32 + quad*8
    const unsigned short* kbase = QKb + (size_t)(b * 4096) * 128 + 64 + l16 * 128 + quad * 8;
    const unsigned short* vbase = Vt + (size_t)(dv0 + l16) * 16384 + b * 4096 + quad * 8;
    const float* mbase = maskx + b * 4096 + quad * 4;

    // prefetch K fragments for iter 0
    short8 kc00 = *(const short8*)(kbase);
    short8 kc01 = *(const short8*)(kbase + 32);
    short8 kc10 = *(const short8*)(kbase + 2048);
    short8 kc11 = *(const short8*)(kbase + 2048 + 32);

    for (int kt = 0; kt < niter; kt++) {
        const int k0 = kt * 32;
        // S^T = K . Q^T : lane holds q-row = l16, keys = quad*4+r (s0), +16 (s1)
        floatx4 s0 = (floatx4)0.f, s1 = (floatx4)0.f;
        s0 = __builtin_amdgcn_mfma_f32_16x16x32_bf16(kc00, qa0, s0, 0, 0, 0);
        s0 = __builtin_amdgcn_mfma_f32_16x16x32_bf16(kc01, qa1, s0, 0, 0, 0);
        s1 = __builtin_amdgcn_mfma_f32_16x16x32_bf16(kc10, qa0, s1, 0, 0, 0);
        s1 = __builtin_amdgcn_mfma_f32_16x16x32_bf16(kc11, qa1, s1, 0, 0, 0);
        // key-padding masks for this iter's 32 keys
        const float4 m0 = *(const float4*)(mbase + k0);
        const float4 m1 = *(const float4*)(mbase + k0 + 16);
        // prefetch next-iter K (uniform scalar clamp keeps it in bounds)
        {
            const int k0n = (k0 + 32 > 4064) ? 4064 : (k0 + 32);
            const unsigned short* kp = kbase + (size_t)k0n * 128;
            kc00 = *(const short8*)kp;
            kc01 = *(const short8*)(kp + 32);
            kc10 = *(const short8*)(kp + 2048);
            kc11 = *(const short8*)(kp + 2048 + 32);
        }
        // masked exp
        float p0[4], p1[4];
#pragma unroll
        for (int r = 0; r < 4; r++) {
            const int kg0 = k0 + quad * 4 + r;
            const bool ok0 = (kg0 <= qrow) && ((m0[r] < -1e30f) == pq);
            p0[r] = ok0 ? __expf(s0[r] * scale) : 0.f;
            const bool ok1 = (kg0 + 16 <= qrow) && ((m1[r] < -1e30f) == pq);
            p1[r] = ok1 ? __expf(s1[r] * scale) : 0.f;
            lacc += p0[r] + p1[r];
        }
        // pack to bf16 pairs and redistribute across quads:
        // word w[kb][p] at quad qs -> target quad kb*2+(qs>>1), slot (qs&1)*2+p
        unsigned w0, w1, w2, w3;
        asm("v_cvt_pk_bf16_f32 %0, %1, %2" : "=v"(w0) : "v"(p0[0]), "v"(p0[1]));
        asm("v_cvt_pk_bf16_f32 %0, %1, %2" : "=v"(w1) : "v"(p0[2]), "v"(p0[3]));
        asm("v_cvt_pk_bf16_f32 %0, %1, %2" : "=v"(w2) : "v"(p1[0]), "v"(p1[1]));
        asm("v_cvt_pk_bf16_f32 %0, %1, %2" : "=v"(w3) : "v"(p1[2]), "v"(p1[3]));
        asm("v_permlane32_swap_b32 %0, %1" : "+v"(w0), "+v"(w2));
        asm("v_permlane16_swap_b32 %0, %1" : "+v"(w0), "+v"(w2));  // w0=a0, w2=a2
        asm("v_permlane32_swap_b32 %0, %1" : "+v"(w1), "+v"(w3));
        asm("v_permlane16_swap_b32 %0, %1" : "+v"(w1), "+v"(w3));  // w1=a1, w3=a3
        uintx4 pw; pw.x = w0; pw.y = w1; pw.z = w2; pw.w = w3;
        const short8 pa = __builtin_bit_cast(short8, pw);
        // PV: acc[cb] += P(16x32) . V(32x16)
        const unsigned short* vp = vbase + k0;
#pragma unroll
        for (int cb = 0; cb < 16; cb++) {
            const short8 vb = *(const short8*)(vp + (size_t)cb * 262144);
            acc[cb] = __builtin_amdgcn_mfma_f32_16x16x32_bf16(pa, vb, acc[cb], 0, 0, 0);
        }
    }

    // row sum for row l16: reduce across quads
    float tot = lacc;
    tot += __shfl_xor(tot, 16);
    tot += __shfl_xor(tot, 32);
    const float inv = 1.f / tot;            // valid for row l16 on every lane
    // PV output rows are quad*4+r -> fetch matching inv via bpermute
    float rinv[4];
#pragma unroll
    for (int r = 0; r < 4; r++) rinv[r] = __shfl(inv, quad * 4 + r);

#pragma unroll
    for (int cb = 0; cb < 16; cb++) {
#pragma unroll
        for (int r = 0; r < 4; r++) {
            const int orow = q0 + rb * 16 + quad * 4 + r;
            out[(size_t)(b * 4096 + orow) * 1024 + dv0 + cb * 16 + l16] = acc[cb][r] * rinv[r];
        }
    }
}

extern "C" void kernel_launch(void* const* d_in, const int* in_sizes, int n_in,
                              void* d_out, int out_size, void* d_ws, size_t ws_size,
                              hipStream_t stream) {
    const float* x  = (const float*)d_in[0];
    const float* Wq = (const float*)d_in[1];
    const float* bq = (const float*)d_in[2];
    const float* Wk = (const float*)d_in[3];
    const float* bk = (const float*)d_in[4];
    const float* Wv = (const float*)d_in[5];
    const float* bv = (const float*)d_in[6];
    const float* mk = (const float*)d_in[7];
    float* out = (float*)d_out;

    const int M = 4 * 4096;  // 16384
    char* ws = (char*)d_ws;
    unsigned short* Xb   = (unsigned short*)ws;                      // 32 MB
    unsigned short* Vt   = (unsigned short*)(ws + (33554432));       // 32 MB (1024 x 16384)
    unsigned short* Wvt  = (unsigned short*)(ws + (67108864));       // 2 MB  (1024 x 1024)
    unsigned short* Wqkt = (unsigned short*)(ws + (69206016));       // 256 KB (128 x 1024)
    unsigned short* QKb  = (unsigned short*)(ws + (69468160));       // 4 MB  (16384 x 128)
    float*          bqk  = (float*)(ws + (73662464));                // 512 B

    conv_x<<<2048, 256, 0, stream>>>(x, Xb);
    transpose_w<<<dim3(16, 16), 256, 0, stream>>>(Wv, Wvt, 1024);
    transpose_w<<<dim3(16, 1), 256, 0, stream>>>(Wq, Wqkt, 64);
    transpose_w<<<dim3(16, 1), 256, 0, stream>>>(Wk, Wqkt + 64 * 1024, 64);
    pack_bias<<<1, 128, 0, stream>>>(bq, bk, bqk);

    gemm_bf16<true ><<<dim3(128, 8), 256, 0, stream>>>(Xb, Wvt, bv, Vt, M, 1024);
    gemm_bf16<false><<<dim3(128, 1), 256, 0, stream>>>(Xb, Wqkt, bqk, QKb, M, 128);

    attn_fused<<<dim3(4 * 64 * 4), 256, 0, stream>>>(QKb, Vt, mk, out);
}

// Round 6
// 391.426 us; speedup vs baseline: 2.1799x; 2.1799x over previous
//
#include <hip/hip_runtime.h>
#include <stdint.h>

typedef __attribute__((ext_vector_type(8))) short short8;
typedef __attribute__((ext_vector_type(4))) float floatx4;

__device__ __forceinline__ unsigned short f2bf(float f) {
    unsigned u = __float_as_uint(f);
    u += 0x7FFFu + ((u >> 16) & 1u);
    return (unsigned short)(u >> 16);
}

__device__ __forceinline__ void gload_lds16(const void* g, void* l) {
    __builtin_amdgcn_global_load_lds(
        (const __attribute__((address_space(1))) unsigned int*)g,
        (__attribute__((address_space(3))) unsigned int*)l, 16, 0, 0);
}

// ---- prep: X fp32 -> bf16 (same layout) ----
__global__ __launch_bounds__(256)
void conv_x(const float* __restrict__ x, unsigned short* __restrict__ xb) {
    const size_t total = (size_t)16384 * 1024;
    for (size_t i = ((size_t)blockIdx.x * 256 + threadIdx.x) * 8; i < total;
         i += (size_t)2048 * 256 * 8) {
        float4 a = *(const float4*)&x[i];
        float4 b = *(const float4*)&x[i + 4];
        uint4 o;
        o.x = f2bf(a.x) | ((unsigned)f2bf(a.y) << 16);
        o.y = f2bf(a.z) | ((unsigned)f2bf(a.w) << 16);
        o.z = f2bf(b.x) | ((unsigned)f2bf(b.y) << 16);
        o.w = f2bf(b.z) | ((unsigned)f2bf(b.w) << 16);
        *(uint4*)&xb[i] = o;
    }
}

// ---- prep: transpose all three W into one Wt[1152][1024] bf16 ----
//      rows 0..1023 = Wv^T, 1024..1087 = Wq^T, 1088..1151 = Wk^T
__global__ __launch_bounds__(256)
void transpose_all(const float* __restrict__ Wv, const float* __restrict__ Wq,
                   const float* __restrict__ Wk, unsigned short* __restrict__ Wt) {
    __shared__ float T[64][65];
    const int t = threadIdx.x;
    const int k0 = blockIdx.x * 64;
    const int y = blockIdx.y;
    const float* src; int N, n0, rowoff;
    if (y < 16)      { src = Wv; N = 1024; n0 = y * 64; rowoff = 0; }
    else if (y == 16){ src = Wq; N = 64;   n0 = 0;      rowoff = 1024; }
    else             { src = Wk; N = 64;   n0 = 0;      rowoff = 1088; }
    const int r = t >> 4, c4 = (t & 15) * 4;
#pragma unroll
    for (int i = 0; i < 4; i++) {
        float4 v = *(const float4*)&src[(size_t)(k0 + r + 16 * i) * N + n0 + c4];
        T[r + 16 * i][c4] = v.x; T[r + 16 * i][c4 + 1] = v.y;
        T[r + 16 * i][c4 + 2] = v.z; T[r + 16 * i][c4 + 3] = v.w;
    }
    __syncthreads();
#pragma unroll
    for (int i = 0; i < 4; i++) {
        const int n = rowoff + n0 + r + 16 * i;
        unsigned short b0 = f2bf(T[c4 + 0][r + 16 * i]);
        unsigned short b1 = f2bf(T[c4 + 1][r + 16 * i]);
        unsigned short b2 = f2bf(T[c4 + 2][r + 16 * i]);
        unsigned short b3 = f2bf(T[c4 + 3][r + 16 * i]);
        uint2 pv;
        pv.x = b0 | ((unsigned)b1 << 16);
        pv.y = b2 | ((unsigned)b3 << 16);
        *(uint2*)&Wt[(size_t)n * 1024 + k0 + c4] = pv;
    }
}

// ---- prep: pack [bv | bq | bk] into bfull[1152] ----
__global__ __launch_bounds__(576)
void pack_bias_all(const float* __restrict__ bv, const float* __restrict__ bq,
                   const float* __restrict__ bk, float* __restrict__ bf) {
    const int t = blockIdx.x * 576 + threadIdx.x;
    if (t < 1024) bf[t] = bv[t];
    else if (t < 1088) bf[t] = bq[t - 1024];
    else if (t < 1152) bf[t] = bk[t - 1088];
}

// ---- fused m97-style 128x128 bf16 GEMM over N=1152 = [V(1024) | QK(128)] ----
//      y<8: C^T store into Vt[n][16384]; y==8: row store into QKb[m][128]
__global__ __launch_bounds__(256)
void gemm_fused(const unsigned short* __restrict__ A,
                const unsigned short* __restrict__ Bt,
                const float* __restrict__ bias,
                unsigned short* __restrict__ Vt,
                unsigned short* __restrict__ QKb)
{
    __shared__ unsigned short As[128 * 32];
    __shared__ unsigned short Bs[128 * 32];
    const int tid = threadIdx.x;
    const int w = tid >> 6, l = tid & 63;
    const int quad = l >> 4, l16 = l & 15;
    const int wr = w >> 1, wc = w & 1;
    const int m0 = blockIdx.x * 128, n0 = blockIdx.y * 128;

    const int lr = l >> 2, lk = (l & 3) * 8;
    const unsigned short* Ag0 = A + (size_t)(m0 + w * 16 + lr) * 1024 + lk;
    const unsigned short* Ag1 = Ag0 + (size_t)64 * 1024;
    const unsigned short* Bg0 = Bt + (size_t)(n0 + w * 16 + lr) * 1024 + lk;
    const unsigned short* Bg1 = Bg0 + (size_t)64 * 1024;
    unsigned short* Al0 = &As[w * 512 + l * 8];
    unsigned short* Bl0 = &Bs[w * 512 + l * 8];

    floatx4 acc[4][4];
#pragma unroll
    for (int i = 0; i < 4; i++)
#pragma unroll
        for (int j = 0; j < 4; j++) acc[i][j] = (floatx4)0.f;

    for (int e0 = 0; e0 < 1024; e0 += 32) {
        gload_lds16(Ag0 + e0, Al0);
        gload_lds16(Ag1 + e0, Al0 + 2048);
        gload_lds16(Bg0 + e0, Bl0);
        gload_lds16(Bg1 + e0, Bl0 + 2048);
        __syncthreads();
        short8 af[4], bf[4];
#pragma unroll
        for (int i = 0; i < 4; i++)
            af[i] = *(const short8*)&As[(wr * 64 + i * 16 + l16) * 32 + quad * 8];
#pragma unroll
        for (int j = 0; j < 4; j++)
            bf[j] = *(const short8*)&Bs[(wc * 64 + j * 16 + l16) * 32 + quad * 8];
#pragma unroll
        for (int i = 0; i < 4; i++)
#pragma unroll
            for (int j = 0; j < 4; j++)
                acc[i][j] = __builtin_amdgcn_mfma_f32_16x16x32_bf16(af[i], bf[j], acc[i][j], 0, 0, 0);
        __syncthreads();
    }

    const bool toQK = (n0 >= 1024);
#pragma unroll
    for (int j = 0; j < 4; j++) {
        const int n = n0 + wc * 64 + j * 16 + l16;
        const float bn = bias[n];
#pragma unroll
        for (int i = 0; i < 4; i++) {
            const int mb = m0 + wr * 64 + i * 16 + quad * 4;
            if (!toQK) {
                unsigned short t[4];
#pragma unroll
                for (int r = 0; r < 4; r++) t[r] = f2bf(acc[i][j][r] + bn);
                uint2 pv;
                pv.x = t[0] | ((unsigned)t[1] << 16);
                pv.y = t[2] | ((unsigned)t[3] << 16);
                *(uint2*)&Vt[(size_t)n * 16384 + mb] = pv;
            } else {
#pragma unroll
                for (int r = 0; r < 4; r++)
                    QKb[(size_t)(mb + r) * 128 + (n - 1024)] = f2bf(acc[i][j][r] + bn);
            }
        }
    }
}

// ---- attention v5 (verified, round-2): relaxed lgkm-only barrier, K/mask
//      prefetch spans iterations, single-buffered V. 512 thr, 8 waves. ----
__global__ __launch_bounds__(512, 4)
void attn_fused(const unsigned short* __restrict__ QKb, // 16384 x 128 bf16 (Q|K)
                const unsigned short* __restrict__ Vt,  // 1024 x 16384 bf16 (dv, bs)
                const float* __restrict__ maskx,        // 4 x 4096
                float* __restrict__ out)                // 4 x 4096 x 1024
{
    __shared__ unsigned short Qs[64 * 72];
    __shared__ unsigned short Ps[2][64 * 40];
    __shared__ float Ls[64];

    const int tid = threadIdx.x;
    const int wave = tid >> 6, lane = tid & 63;
    const int quad = lane >> 4, l16 = lane & 15;
    const int bid = blockIdx.x;
    // bid&7 = (b,dvh): same combo -> same XCD slot under round-robin dispatch
    const int dvh = bid & 1;
    const int b = (bid >> 1) & 3;
    const int t = bid >> 3;                 // 0..63
    const int qt = (t < 32) ? (63 - t) : (t - 32);  // pair sums to 63 per CU
    const int q0 = qt * 64;
    const int gq0 = b * 4096 + q0;

    if (tid < 64) Ls[tid] = 0.f;
    {
        const int r = tid >> 3, c = (tid & 7) * 8;
        uint4 v = *(const uint4*)&QKb[(size_t)(gq0 + r) * 128 + c];
        *(uint4*)&Qs[r * 72 + c] = v;
    }
    __syncthreads();

    const int rb = wave >> 1;   // S-phase row block 0..3
    const int kb = wave & 1;    // S-phase key sub-block 0..1
    bool pq[4];
#pragma unroll
    for (int r = 0; r < 4; r++)
        pq[r] = maskx[b * 4096 + q0 + rb * 16 + quad * 4 + r] < -1e30f;

    const short8 qa0 = *(const short8*)&Qs[(rb * 16 + l16) * 72 + quad * 8];
    const short8 qa1 = *(const short8*)&Qs[(rb * 16 + l16) * 72 + 32 + quad * 8];

    floatx4 acc[4][4];
#pragma unroll
    for (int i = 0; i < 4; i++)
#pragma unroll
        for (int j = 0; j < 4; j++) acc[i][j] = (floatx4)0.f;
    float lacc[4] = {0.f, 0.f, 0.f, 0.f};

    const int niter = 2 * qt + 2;
    const float scale = 0.125f;
    const int dv0 = dvh * 512 + wave * 64;

    // per-lane bases
    const unsigned short* kptr = QKb + ((size_t)(b * 4096 + kb * 16 + l16) * 128 + 64 + quad * 8);
    const float* mptr = maskx + b * 4096 + kb * 16 + l16;
    size_t voff[4];
#pragma unroll
    for (int cb = 0; cb < 4; cb++)
        voff[cb] = (size_t)(dv0 + cb * 16 + l16) * 16384 + b * 4096 + quad * 8;

    // prefetch for iter 0: K fragments + mask value
    short8 kc0 = *(const short8*)kptr;
    short8 kc1 = *(const short8*)(kptr + 32);
    float mval = *mptr;

    for (int kt = 0; kt < niter; kt++) {
        const int k0 = kt * 32;
        // V loads for THIS iter issued first (consumed after the barrier)
        short8 vb[4];
#pragma unroll
        for (int cb = 0; cb < 4; cb++)
            vb[cb] = *(const short8*)&Vt[voff[cb] + k0];
        // S = Q K^T using prefetched K
        floatx4 s = (floatx4)0.f;
        s = __builtin_amdgcn_mfma_f32_16x16x32_bf16(qa0, kc0, s, 0, 0, 0);
        s = __builtin_amdgcn_mfma_f32_16x16x32_bf16(qa1, kc1, s, 0, 0, 0);
        // prefetch K + mask for next iter (clamped to stay in-bounds);
        // these stay in flight across the relaxed barrier below
        const bool pk = mval < -1e30f;
        {
            int kn = k0 + 32 + kb * 16 + l16;
            if (kn > 4095) kn = 4095;
            const unsigned short* np = QKb + ((size_t)(b * 4096 + kn) * 128 + 64 + quad * 8);
            kc0 = *(const short8*)np;
            kc1 = *(const short8*)(np + 32);
            mval = maskx[b * 4096 + kn];
        }
        const int kg = k0 + kb * 16 + l16;
        unsigned short pbits[4];
#pragma unroll
        for (int r = 0; r < 4; r++) {
            const int qrow = q0 + rb * 16 + quad * 4 + r;
            float p = 0.f;
            if (kg <= qrow && pk == pq[r]) p = __expf(s[r] * scale);
            lacc[r] += p;
            pbits[r] = f2bf(p);
        }
        // write P (double-buffered), then lgkm-only barrier: global loads stay in flight
        unsigned short* Pw = Ps[kt & 1];
#pragma unroll
        for (int r = 0; r < 4; r++)
            Pw[(rb * 16 + quad * 4 + r) * 40 + kb * 16 + l16] = pbits[r];
        asm volatile("s_waitcnt lgkmcnt(0)" ::: "memory");
        __builtin_amdgcn_s_barrier();
        __builtin_amdgcn_sched_barrier(0);
        const unsigned short* Pr = Ps[kt & 1];
        short8 pa[4];
#pragma unroll
        for (int r2 = 0; r2 < 4; r2++)
            pa[r2] = *(const short8*)&Pr[(r2 * 16 + l16) * 40 + quad * 8];
#pragma unroll
        for (int cb = 0; cb < 4; cb++)
#pragma unroll
            for (int r2 = 0; r2 < 4; r2++)
                acc[r2][cb] = __builtin_amdgcn_mfma_f32_16x16x32_bf16(pa[r2], vb[cb], acc[r2][cb], 0, 0, 0);
    }

#pragma unroll
    for (int r = 0; r < 4; r++) {
        float v = lacc[r];
        v += __shfl_xor(v, 1);
        v += __shfl_xor(v, 2);
        v += __shfl_xor(v, 4);
        v += __shfl_xor(v, 8);
        if (l16 == 0) atomicAdd(&Ls[rb * 16 + quad * 4 + r], v);
    }
    __syncthreads();

#pragma unroll
    for (int r2 = 0; r2 < 4; r2++) {
#pragma unroll
        for (int r = 0; r < 4; r++) {
            const int qrow = q0 + r2 * 16 + quad * 4 + r;
            const float inv = 1.f / Ls[r2 * 16 + quad * 4 + r];
#pragma unroll
            for (int cb = 0; cb < 4; cb++)
                out[(size_t)(b * 4096 + qrow) * 1024 + dv0 + cb * 16 + l16] = acc[r2][cb][r] * inv;
        }
    }
}

extern "C" void kernel_launch(void* const* d_in, const int* in_sizes, int n_in,
                              void* d_out, int out_size, void* d_ws, size_t ws_size,
                              hipStream_t stream) {
    const float* x  = (const float*)d_in[0];
    const float* Wq = (const float*)d_in[1];
    const float* bq = (const float*)d_in[2];
    const float* Wk = (const float*)d_in[3];
    const float* bk = (const float*)d_in[4];
    const float* Wv = (const float*)d_in[5];
    const float* bv = (const float*)d_in[6];
    const float* mk = (const float*)d_in[7];
    float* out = (float*)d_out;

    char* ws = (char*)d_ws;
    unsigned short* Xb   = (unsigned short*)ws;                      // 32 MB
    unsigned short* Vt   = (unsigned short*)(ws + (33554432));       // 32 MB (1024 x 16384)
    unsigned short* Wt   = (unsigned short*)(ws + (67108864));       // 2.25 MB (1152 x 1024)
    unsigned short* QKb  = (unsigned short*)(ws + (69468160));       // 4 MB  (16384 x 128)
    float*          bfull= (float*)(ws + (73662464));                // 4.5 KB

    conv_x<<<2048, 256, 0, stream>>>(x, Xb);
    transpose_all<<<dim3(16, 18), 256, 0, stream>>>(Wv, Wq, Wk, Wt);
    pack_bias_all<<<2, 576, 0, stream>>>(bv, bq, bk, bfull);

    gemm_fused<<<dim3(128, 9), 256, 0, stream>>>(Xb, Wt, bfull, Vt, QKb);

    attn_fused<<<dim3(4 * 64 * 2), 512, 0, stream>>>(QKb, Vt, mk, out);
}